// Round 6
// baseline (745.109 us; speedup 1.0000x reference)
//
#include <hip/hip_runtime.h>
#include <hip/hip_cooperative_groups.h>

namespace cg = cooperative_groups;

using u16 = unsigned short;
typedef __bf16 bf16x8 __attribute__((ext_vector_type(8)));
typedef unsigned short u16x8 __attribute__((ext_vector_type(8)));
typedef float floatx4 __attribute__((ext_vector_type(4)));

#define D_ 1024
#define T_ 2048

__device__ __forceinline__ u16 f2bf(float f) {
  union { float f; unsigned u; } c; c.f = f;
  unsigned u = c.u;
  u += 0x7fffu + ((u >> 16) & 1u);   // round-to-nearest-even
  return (u16)(u >> 16);
}
__device__ __forceinline__ float bf2f(u16 h) {
  union { unsigned u; float f; } c; c.u = ((unsigned)h) << 16; return c.f;
}

__device__ __forceinline__ void st_out(float* p, float v) { *p = v; }
__device__ __forceinline__ void st_out(u16* p, float v) { *p = f2bf(v); }

__device__ __forceinline__ void load16(const u16* g, u16* l) {
  __builtin_amdgcn_global_load_lds(
      (const __attribute__((address_space(1))) void*)g,
      (__attribute__((address_space(3))) void*)l, 16, 0, 0);
}

#define TILE 128
#define BK 64

// 128x128 tile GEMM, BK=64, bf16 in / fp32 acc. LDS chunks XOR-swizzled
// (slot = m ^ (r&7)) -> 0 bank conflicts (verified R3).
template<typename OutT>
__device__ __forceinline__ void gemm_core(
    u16* As, u16* Bs,
    const u16* __restrict__ A, int lda,
    const u16* __restrict__ Bt, int ldb,
    OutT* __restrict__ C, int ldc,
    int kmax, int bx, int by)
{
  const u16* Ab = A + (long)by * TILE * lda;
  const u16* Bb = Bt + (long)bx * TILE * ldb;

  int tid = threadIdx.x;
  int lane = tid & 63;
  int wm = ((tid >> 7) & 1) * 64;
  int wn = ((tid >> 6) & 1) * 64;

  floatx4 acc[4][4] = {};
  int arow = wm + (lane & 15);
  int brow = wn + (lane & 15);
  int q = lane >> 4;

  for (int k0 = 0; k0 < kmax; k0 += BK) {
    __syncthreads();
#pragma unroll
    for (int h = 0; h < 4; h++) {
      int cc = tid + h * 256;
      int row = cc >> 3, gm = (cc & 7) ^ (row & 7);
      load16(Ab + (long)row * lda + k0 + gm * 8, &As[cc * 8]);
    }
#pragma unroll
    for (int h = 0; h < 4; h++) {
      int cc = tid + h * 256;
      int row = cc >> 3, gm = (cc & 7) ^ (row & 7);
      load16(Bb + (long)row * ldb + k0 + gm * 8, &Bs[cc * 8]);
    }
    __builtin_amdgcn_s_waitcnt(0);
    __syncthreads();

#pragma unroll
    for (int kp = 0; kp < 2; kp++) {
      bf16x8 a[4], b[4];
#pragma unroll
      for (int i = 0; i < 4; i++) {
        int r = arow + i * 16;
        a[i] = *(const bf16x8*)&As[(r * 8 + ((kp * 4 + q) ^ (r & 7))) * 8];
      }
#pragma unroll
      for (int j = 0; j < 4; j++) {
        int r = brow + j * 16;
        b[j] = *(const bf16x8*)&Bs[(r * 8 + ((kp * 4 + q) ^ (r & 7))) * 8];
      }
#pragma unroll
      for (int i = 0; i < 4; i++)
#pragma unroll
        for (int j = 0; j < 4; j++)
          acc[i][j] = __builtin_amdgcn_mfma_f32_16x16x32_bf16(a[i], b[j], acc[i][j], 0, 0, 0);
    }
  }

  // epilogue: C/D layout col=lane&15, row=(lane>>4)*4+reg  [m89-verified]
  int colbase = bx * TILE + wn + (lane & 15);
  int rowbase = by * TILE + wm + ((lane >> 4) << 2);
#pragma unroll
  for (int i = 0; i < 4; i++)
#pragma unroll
    for (int j = 0; j < 4; j++) {
      int col = colbase + j * 16;
#pragma unroll
      for (int r = 0; r < 4; r++)
        st_out(&C[(long)(rowbase + i * 16 + r) * ldc + col], acc[i][j][r]);
    }
}

// ---------- phases (grid-size agnostic; b = blockIdx.x, G = gridDim.x) ----------

// converts: [0,8192) x | [8192,8704) Wq*1/32 | [8704,9216) Wk | [9216,9472) Wv^T
__device__ __forceinline__ void ph_cvt(
    const float* x, const float* Wq, const float* Wk, const float* Wv,
    u16* xb, u16* Wqb, u16* Wkb, u16* WvT, char* smem, int b, int G)
{
  int tid = threadIdx.x;
  for (int jb = b; jb < 9472; jb += G) {
    if (jb < 9216) {
      const float* src; u16* dst; float sc; long base;
      if (jb < 8192)      { src = x;  dst = xb;  sc = 1.0f;     base = (long)jb * 2048; }
      else if (jb < 8704) { src = Wq; dst = Wqb; sc = 0.03125f; base = (long)(jb - 8192) * 2048; }
      else                { src = Wk; dst = Wkb; sc = 1.0f;     base = (long)(jb - 8704) * 2048; }
      const float4* s4 = (const float4*)(src + base);
      float4 v0 = s4[tid * 2], v1 = s4[tid * 2 + 1];
      u16x8 r;
      r[0] = f2bf(v0.x * sc); r[1] = f2bf(v0.y * sc);
      r[2] = f2bf(v0.z * sc); r[3] = f2bf(v0.w * sc);
      r[4] = f2bf(v1.x * sc); r[5] = f2bf(v1.y * sc);
      r[6] = f2bf(v1.z * sc); r[7] = f2bf(v1.w * sc);
      *(u16x8*)(dst + base + (long)tid * 8) = r;
    } else {
      int tj = jb - 9216;
      int e0 = (tj & 15) * 64, d0 = (tj >> 4) * 64;
      float* t = (float*)smem;               // [64][65]
      int c = tid & 63, r = tid >> 6;
      __syncthreads();
      for (int rr = r; rr < 64; rr += 4)
        t[rr * 65 + c] = Wv[(long)(d0 + rr) * D_ + e0 + c];
      __syncthreads();
      for (int rr = r; rr < 64; rr += 4)
        WvT[(long)(e0 + rr) * D_ + d0 + c] = f2bf(t[c * 65 + rr]);
    }
  }
}

// NT partials, split-K x4: 256 jobs (tile 0..63 x kslice 0..3), K=256 each
__device__ __forceinline__ void ph_nt(const u16* Wqb, const u16* Wkb,
                                      float* NTpart, u16* As, u16* Bs, int b, int G)
{
  for (int j = b; j < 256; j += G) {
    int ks = j & 3, t = j >> 2;
    gemm_core<float>(As, Bs, Wkb + ks * 256, D_, Wqb + ks * 256, D_,
                     NTpart + (long)ks * D_ * D_, D_, 256, t & 7, t >> 3);
  }
}

// NT = bf16(sum of 4 fp32 partials)
__device__ __forceinline__ void ph_ntred(const float* NTpart, u16* NT, int b, int G)
{
  for (int u = b * 256 + threadIdx.x; u < 131072; u += G * 256) {
    long i = (long)u * 8;
    float s[8];
#pragma unroll
    for (int k = 0; k < 8; k++) s[k] = 0.f;
#pragma unroll
    for (int p = 0; p < 4; p++) {
      const float4* q4 = (const float4*)(NTpart + (long)p * D_ * D_ + i);
      float4 a0 = q4[0], a1 = q4[1];
      s[0] += a0.x; s[1] += a0.y; s[2] += a0.z; s[3] += a0.w;
      s[4] += a1.x; s[5] += a1.y; s[6] += a1.z; s[7] += a1.w;
    }
    u16x8 o;
#pragma unroll
    for (int k = 0; k < 8; k++) o[k] = f2bf(s[k]);
    *(u16x8*)(NT + i) = o;
  }
}

// Y = xb @ NT^T, 1024 jobs, XCD-contiguous
__device__ __forceinline__ void ph_y(const u16* xb, const u16* NT, u16* Yb,
                                     u16* As, u16* Bs, int b, int G)
{
  for (int j = b; j < 1024; j += G) {
    int t = ((j & 7) << 7) | (j >> 3);
    gemm_core<u16>(As, Bs, xb, D_, NT, D_, Yb, D_, D_, t & 7, t >> 3);
  }
}

// tri (1088 causal S-tiles) + VT (1024 tiles) merged; all K=1024 uniform
__device__ __forceinline__ void ph_trivt(const u16* Yb, const u16* xb, u16* S,
                                         const u16* WvT, u16* VT,
                                         u16* As, u16* Bs, int b, int G)
{
  for (int j = b; j < 2112; j += G) {
    if (j < 1088) {
      int zi = j / 136, tp = j - zi * 136;
      int t = (tp & 7) * 17 + (tp >> 3);
      int r = (int)((sqrtf(8.f * t + 1.f) - 1.f) * 0.5f);
      while ((r + 1) * (r + 2) / 2 <= t) ++r;
      while (r * (r + 1) / 2 > t) --r;
      int c = t - r * (r + 1) / 2;
      gemm_core<u16>(As, Bs, Yb + (long)zi * T_ * D_, D_,
                     xb + (long)zi * T_ * D_, D_,
                     S + (long)zi * T_ * T_, T_, D_, c, r);
    } else {
      int LL = j - 1088;
      int xj = LL & 7, m = LL >> 3;
      gemm_core<u16>(As, Bs, WvT, D_, xb, D_, VT, 8 * T_, D_,
                     16 * xj + (m >> 3), m & 7);
    }
  }
}

// causal softmax in place, gated to 128-tile boundary
__device__ __forceinline__ void ph_smx(u16* S, float* red, int b, int G)
{
  int tid = threadIdx.x, lane = tid & 63, wid = tid >> 6, i0 = tid * 8;
  for (int rr = b; rr < 16384; rr += G) {
    u16* Prow = S + (long)rr * T_;
    int row = rr & (T_ - 1), n = row + 1, nw = ((row >> 7) + 1) << 7;
    bool act = i0 < nw;
    u16x8 pv = {};
    if (act) pv = *(const u16x8*)(Prow + i0);
    float v[8], lmax = -3.0e38f;
#pragma unroll
    for (int j = 0; j < 8; j++) {
      v[j] = (i0 + j < n) ? bf2f(pv[j]) : -3.0e38f;
      lmax = fmaxf(lmax, v[j]);
    }
#pragma unroll
    for (int o = 32; o > 0; o >>= 1) lmax = fmaxf(lmax, __shfl_down(lmax, o, 64));
    if (lane == 0) red[wid] = lmax;
    __syncthreads();
    float m = fmaxf(fmaxf(red[0], red[1]), fmaxf(red[2], red[3]));
    float lsum = 0.f;
#pragma unroll
    for (int j = 0; j < 8; j++) {
      float e = (i0 + j < n) ? __expf(v[j] - m) : 0.f;
      v[j] = e;
      lsum += e;
    }
#pragma unroll
    for (int o = 32; o > 0; o >>= 1) lsum += __shfl_down(lsum, o, 64);
    if (lane == 0) red[4 + wid] = lsum;
    __syncthreads();
    float inv = 1.0f / (red[4] + red[5] + red[6] + red[7]);
    if (act) {
      u16x8 w;
#pragma unroll
      for (int j = 0; j < 8; j++) w[j] = f2bf(v[j] * inv);
      *(u16x8*)(Prow + i0) = w;
    }
    __syncthreads();
  }
}

// O = P @ V, causal K-trim. J bits: xj[0:2] bt[3:5] bx[6:8] u[9].
// u=0 -> long row (15-xj), u=1 -> short row (xj): launch-order = longest-first;
// at G=512 each block gets exactly one long + one short (17 K-tiles).
__device__ __forceinline__ void ph_opv(const u16* S, const u16* VT, float* out,
                                       u16* As, u16* Bs, int b, int G)
{
  for (int J = b; J < 1024; J += G) {
    int xj = J & 7, bt = (J >> 3) & 7, bx = (J >> 6) & 7, u = J >> 9;
    int by = u ? xj : 15 - xj;
    gemm_core<float>(As, Bs, S + (long)bt * T_ * T_, T_,
                     VT + (long)bt * T_, 8 * T_,
                     out + (long)bt * T_ * D_, D_, (by + 1) * TILE, bx, by);
  }
}

// ---------- cooperative mega-kernel ----------
__global__ __launch_bounds__(256, 2)
void attn_mega(const float* __restrict__ x, const float* __restrict__ Wq,
               const float* __restrict__ Wk, const float* __restrict__ Wv,
               u16* xb, u16* Wqb, u16* Wkb, u16* WvT,
               float* NTpart, u16* NT, u16* Yb, u16* VT, u16* S, float* out)
{
  __shared__ __align__(16) char smem[32768];
  u16* As = (u16*)smem;
  u16* Bs = (u16*)(smem + 16384);
  cg::grid_group grid = cg::this_grid();
  int b = blockIdx.x, G = gridDim.x;

  ph_cvt(x, Wq, Wk, Wv, xb, Wqb, Wkb, WvT, smem, b, G);
  grid.sync();
  ph_nt(Wqb, Wkb, NTpart, As, Bs, b, G);
  grid.sync();
  ph_ntred(NTpart, NT, b, G);
  grid.sync();
  ph_y(xb, NT, Yb, As, Bs, b, G);
  grid.sync();
  ph_trivt(Yb, xb, S, WvT, VT, As, Bs, b, G);
  grid.sync();
  ph_smx(S, (float*)smem, b, G);
  grid.sync();
  ph_opv(S, VT, out, As, Bs, b, G);
}

// ---------- fallback wrappers (identical math, regular dispatches) ----------
__global__ __launch_bounds__(256) void k_cvt(
    const float* x, const float* Wq, const float* Wk, const float* Wv,
    u16* xb, u16* Wqb, u16* Wkb, u16* WvT)
{
  __shared__ __align__(16) char smem[32768];
  ph_cvt(x, Wq, Wk, Wv, xb, Wqb, Wkb, WvT, smem, blockIdx.x, gridDim.x);
}
__global__ __launch_bounds__(256, 2) void k_nt(const u16* Wqb, const u16* Wkb, float* NTpart)
{
  __shared__ __align__(16) char smem[32768];
  ph_nt(Wqb, Wkb, NTpart, (u16*)smem, (u16*)(smem + 16384), blockIdx.x, gridDim.x);
}
__global__ __launch_bounds__(256) void k_ntred(const float* NTpart, u16* NT)
{
  ph_ntred(NTpart, NT, blockIdx.x, gridDim.x);
}
__global__ __launch_bounds__(256, 2) void k_y(const u16* xb, const u16* NT, u16* Yb)
{
  __shared__ __align__(16) char smem[32768];
  ph_y(xb, NT, Yb, (u16*)smem, (u16*)(smem + 16384), blockIdx.x, gridDim.x);
}
__global__ __launch_bounds__(256, 2) void k_trivt(const u16* Yb, const u16* xb, u16* S,
                                                  const u16* WvT, u16* VT)
{
  __shared__ __align__(16) char smem[32768];
  ph_trivt(Yb, xb, S, WvT, VT, (u16*)smem, (u16*)(smem + 16384), blockIdx.x, gridDim.x);
}
__global__ __launch_bounds__(256) void k_smx(u16* S)
{
  __shared__ float red[8];
  ph_smx(S, red, blockIdx.x, gridDim.x);
}
__global__ __launch_bounds__(256, 2) void k_opv(const u16* S, const u16* VT, float* out)
{
  __shared__ __align__(16) char smem[32768];
  ph_opv(S, VT, out, (u16*)smem, (u16*)(smem + 16384), blockIdx.x, gridDim.x);
}

extern "C" void kernel_launch(void* const* d_in, const int* in_sizes, int n_in,
                              void* d_out, int out_size, void* d_ws, size_t ws_size,
                              hipStream_t stream)
{
  const float* x  = (const float*)d_in[0];
  const float* Wq = (const float*)d_in[1];
  const float* Wk = (const float*)d_in[2];
  const float* Wv = (const float*)d_in[3];
  float* out = (float*)d_out;
  char* ws = (char*)d_ws;

  // layout (MB): xb 0-32 | WvT 32-34 | NT 34-36 | Yb 36-68 | VT 68-100 |
  //              S 100-164 | NTpart 164-180 | Wqb 180-182 | Wkb 182-184
  u16*   xb     = (u16*)(ws);
  u16*   WvT    = (u16*)(ws + (32ul  << 20));
  u16*   NT     = (u16*)(ws + (34ul  << 20));
  u16*   Yb     = (u16*)(ws + (36ul  << 20));
  u16*   VT     = (u16*)(ws + (68ul  << 20));
  u16*   S      = (u16*)(ws + (100ul << 20));
  float* NTpart = (float*)(ws + (164ul << 20));
  u16*   Wqb    = (u16*)(ws + (180ul << 20));
  u16*   Wkb    = (u16*)(ws + (182ul << 20));

  void* args[] = { &x, &Wq, &Wk, &Wv, &xb, &Wqb, &Wkb, &WvT,
                   &NTpart, &NT, &Yb, &VT, &S, &out };
  hipError_t e = hipLaunchCooperativeKernel((void*)attn_mega, dim3(512), dim3(256),
                                            args, 0, stream);
  if (e != hipSuccess) {
    (void)hipGetLastError();
    e = hipLaunchCooperativeKernel((void*)attn_mega, dim3(256), dim3(256),
                                   args, 0, stream);
  }
  if (e != hipSuccess) {
    (void)hipGetLastError();
    k_cvt  <<<dim3(2368), 256, 0, stream>>>(x, Wq, Wk, Wv, xb, Wqb, Wkb, WvT);
    k_nt   <<<dim3(256),  256, 0, stream>>>(Wqb, Wkb, NTpart);
    k_ntred<<<dim3(512),  256, 0, stream>>>(NTpart, NT);
    k_y    <<<dim3(1024), 256, 0, stream>>>(xb, NT, Yb);
    k_trivt<<<dim3(2112), 256, 0, stream>>>(Yb, xb, S, WvT, VT);
    k_smx  <<<dim3(4096), 256, 0, stream>>>(S);
    k_opv  <<<dim3(1024), 256, 0, stream>>>(S, VT, out);
  }
}